// Round 2
// baseline (320.909 us; speedup 1.0000x reference)
//
#include <hip/hip_runtime.h>
#include <hip/hip_bf16.h>
#include <stdint.h>

#define NB 2
#define NS 4096
#define ND 768
#define NH 12
#define NW 128
#define NDFF 3072
#define NHD 64
#define NCH 32   // NS/NW

typedef __attribute__((ext_vector_type(8))) short bf16x8;
typedef __attribute__((ext_vector_type(4))) short s16x4;
typedef __attribute__((ext_vector_type(4))) float f32x4;

__device__ __forceinline__ float bf2f(short u) {
    union { unsigned int i; float f; } c;
    c.i = ((unsigned int)(unsigned short)u) << 16;
    return c.f;
}
__device__ __forceinline__ short f2bf(float f) {
    union { float f; unsigned int i; } c;
    c.f = f;
    unsigned int x = c.i;
    return (short)((x + 0x7fffu + ((x >> 16) & 1u)) >> 16);
}

__device__ __forceinline__ void gload_lds16(const void* g, void* l) {
    __builtin_amdgcn_global_load_lds(
        (const __attribute__((address_space(1))) void*)g,
        (__attribute__((address_space(3))) void*)l, 16, 0, 0);
}

// ---------------- cast f32 -> bf16 (vectorized) ----------------
__global__ __launch_bounds__(256) void cast_bf16(const float* __restrict__ in,
                                                 short* __restrict__ out, int n4) {
    int i = blockIdx.x * 256 + threadIdx.x;
    if (i < n4) {
        f32x4 v = ((const f32x4*)in)[i];
        s16x4 o;
        o[0] = f2bf(v[0]); o[1] = f2bf(v[1]); o[2] = f2bf(v[2]); o[3] = f2bf(v[3]);
        ((s16x4*)out)[i] = o;
    }
}

// ---------------- transpose + cast: in[K][N] f32 -> out[N][K] bf16 ----------------
__global__ __launch_bounds__(256) void transpose_cast(const float* __restrict__ in,
                                                      short* __restrict__ out,
                                                      int K, int N) {
    __shared__ float tile[32][33];
    int kb = blockIdx.y * 32, nb = blockIdx.x * 32;
    int tx = threadIdx.x & 31, ty = threadIdx.x >> 5;   // ty 0..7
    #pragma unroll
    for (int r = ty; r < 32; r += 8)
        tile[r][tx] = in[(long)(kb + r) * N + nb + tx];
    __syncthreads();
    #pragma unroll
    for (int r = ty; r < 32; r += 8)
        out[(long)(nb + r) * K + kb + tx] = f2bf(tile[tx][r]);
}

// ---------------- GEMM (m97 structure): C = A[M][K] @ Bt[N][K]^T + bias ----------------
// BK=32, linear LDS [128][32], global_load_lds 16B staging, ds_read_b128 frags.
// MODE 0: (acc+bias)*scale -> bf16 (B,H,S,HD)      (q with scale=0.125, k with scale=1)
// MODE 1: (acc+bias)      -> bf16 (B,H,HD,S)      (v, transposed for attention)
// MODE 2: relu(acc+bias)  -> bf16 [M][NDFF]       (FFN1 hidden)
// MODE 3: acc+bias+xres   -> f32  [M][ND]         (FFN2: y = x + ffn2)
template<int MODE>
__global__ __launch_bounds__(256) void gemm_bt(
    const short* __restrict__ A,
    const short* __restrict__ Bt,
    const float* __restrict__ bias,
    float scale,
    void* __restrict__ outp,
    const float* __restrict__ xres,
    int M, int N, int K)
{
    __shared__ short As[128 * 32];
    __shared__ short Bs[128 * 32];
    int n0 = blockIdx.x * 128, m0 = blockIdx.y * 128;
    int tid = threadIdx.x;
    int wid = tid >> 6, lane = tid & 63;
    int wr = wid >> 1, wc = wid & 1;          // 2x2 waves, each 64x64
    int g = lane >> 4, lr = lane & 15;
    f32x4 acc[4][4];
    #pragma unroll
    for (int a = 0; a < 4; ++a)
        #pragma unroll
        for (int c = 0; c < 4; ++c)
            acc[a][c] = (f32x4){0.f, 0.f, 0.f, 0.f};

    // staging geometry: chunk j (j=0..7) = 16 rows = 1024B; wave w owns chunks w, w+4.
    // lane l -> row j*16 + l/4, element col (l&3)*8; LDS byte = j*1024 + l*16 (linear).
    int lr4 = lane >> 2;
    int lc8 = (lane & 3) << 3;
    const short* aG0 = &A[(long)(m0 + wid * 16 + lr4) * K + lc8];
    const short* aG1 = aG0 + (long)64 * K;
    const short* bG0 = &Bt[(long)(n0 + wid * 16 + lr4) * K + lc8];
    const short* bG1 = bG0 + (long)64 * K;
    short* aL0 = &As[wid * 16 * 32];
    short* aL1 = &As[(64 + wid * 16) * 32];
    short* bL0 = &Bs[wid * 16 * 32];
    short* bL1 = &Bs[(64 + wid * 16) * 32];

    for (int k0 = 0; k0 < K; k0 += 32) {
        gload_lds16(aG0 + k0, aL0);
        gload_lds16(aG1 + k0, aL1);
        gload_lds16(bG0 + k0, bL0);
        gload_lds16(bG1 + k0, bL1);
        __syncthreads();
        bf16x8 af[4], bfr[4];
        #pragma unroll
        for (int mt = 0; mt < 4; ++mt)
            af[mt] = *(const bf16x8*)&As[(wr * 64 + mt * 16 + lr) * 32 + (g << 3)];
        #pragma unroll
        for (int nt = 0; nt < 4; ++nt)
            bfr[nt] = *(const bf16x8*)&Bs[(wc * 64 + nt * 16 + lr) * 32 + (g << 3)];
        #pragma unroll
        for (int mt = 0; mt < 4; ++mt)
            #pragma unroll
            for (int nt = 0; nt < 4; ++nt)
                acc[mt][nt] = __builtin_amdgcn_mfma_f32_16x16x32_bf16(
                    af[mt], bfr[nt], acc[mt][nt], 0, 0, 0);
        __syncthreads();
    }

    int mr0 = m0 + wr * 64;
    int nc0 = n0 + wc * 64;
    #pragma unroll
    for (int mt = 0; mt < 4; ++mt) {
        #pragma unroll
        for (int nt = 0; nt < 4; ++nt) {
            int col = nc0 + nt * 16 + lr;
            float bv = bias[col];
            if (MODE == 1) {
                int m = mr0 + mt * 16 + (g << 2);
                int bb = m >> 12, s = m & (NS - 1);
                int hh = col >> 6, hd = col & 63;
                s16x4 ov;
                ov[0] = f2bf(acc[mt][nt][0] + bv);
                ov[1] = f2bf(acc[mt][nt][1] + bv);
                ov[2] = f2bf(acc[mt][nt][2] + bv);
                ov[3] = f2bf(acc[mt][nt][3] + bv);
                *(s16x4*)&((short*)outp)[((long)(bb * NH + hh) * NHD + hd) * NS + s] = ov;
            } else {
                #pragma unroll
                for (int i = 0; i < 4; ++i) {
                    int m = mr0 + mt * 16 + (g << 2) + i;
                    float v = acc[mt][nt][i];
                    if (MODE == 0) {
                        v = (v + bv) * scale;
                        int bb = m >> 12, s = m & (NS - 1);
                        int hh = col >> 6, hd = col & 63;
                        ((short*)outp)[((long)(bb * NH + hh) * NS + s) * NHD + hd] = f2bf(v);
                    } else if (MODE == 2) {
                        v = fmaxf(v + bv, 0.f);
                        ((short*)outp)[(long)m * NDFF + col] = f2bf(v);
                    } else {
                        v = v + bv + xres[(long)m * ND + col];
                        ((float*)outp)[(long)m * ND + col] = v;
                    }
                }
            }
        }
    }
}

// ---------------- band attention ----------------
#define KLD 72    // 64 + 8 pad (bf16)
#define PLD 392   // 384 + 8 pad (bf16)
#define ATT_LDS (384 * KLD * 2 + 128 * PLD * 2)   // 55296 + 100352 = 155648 B

__global__ __launch_bounds__(512) void attn_kernel(
    const short* __restrict__ qg,   // (B,H,S,HD) bf16, pre-scaled
    const short* __restrict__ kg,   // (B,H,S,HD) bf16
    const short* __restrict__ vtg,  // (B,H,HD,S) bf16
    const float* __restrict__ src,  // (B,S,D) f32
    float* __restrict__ attw,       // (B,H,S,257) f32
    float* __restrict__ x,          // (B,S,D) f32
    short* __restrict__ xb)         // (B,S,D) bf16
{
    extern __shared__ char smem[];
    short* kv = (short*)smem;                     // K tile [384][KLD] then Vt [64][PLD]
    short* pl = (short*)(smem + 384 * KLD * 2);   // P [128][PLD], normalized probs

    int blk = blockIdx.x;
    int ch = blk & 31;
    int tmp = blk >> 5;
    int h = tmp % NH;
    int b = tmp / NH;
    int tid = threadIdx.x;
    int wid = tid >> 6;
    int lane = tid & 63;
    int g = lane >> 4, lr = lane & 15;
    long bh = (long)(b * NH + h);
    long kbase = bh * NS * NHD;
    int srow0 = ch * NW;

    // stage K rows j=0..383 (key pos = srow0-128+j), zero-fill OOB
    #pragma unroll
    for (int it = 0; it < 6; ++it) {
        int idx = it * 512 + tid;
        int j = idx >> 3;
        int c = (idx & 7) << 3;
        int s = srow0 - NW + j;
        bf16x8 v = {};
        if (s >= 0 && s < NS)
            v = *(const bf16x8*)&kg[kbase + (long)s * NHD + c];
        *(bf16x8*)&kv[j * KLD + c] = v;
    }

    // Q fragments for this wave's 16 rows
    int t0 = wid << 4;
    bf16x8 aq[2];
    #pragma unroll
    for (int kk = 0; kk < 2; ++kk)
        aq[kk] = *(const bf16x8*)&qg[kbase + (long)(srow0 + t0 + lr) * NHD + (kk << 5) + (g << 3)];

    __syncthreads();

    // scores: 24 col-tiles of 16, K=64
    f32x4 sc[24];
    #pragma unroll
    for (int jt = 0; jt < 24; ++jt) {
        f32x4 a = (f32x4){0.f, 0.f, 0.f, 0.f};
        #pragma unroll
        for (int kk = 0; kk < 2; ++kk) {
            bf16x8 bk = *(const bf16x8*)&kv[(jt * 16 + lr) * KLD + (kk << 5) + (g << 3)];
            a = __builtin_amdgcn_mfma_f32_16x16x32_bf16(aq[kk], bk, a, 0, 0, 0);
        }
        sc[jt] = a;
    }

    // mask + row max (rows of this lane: t = t0 + g*4 + i; col j = jt*16 + lr)
    float mx[4] = {-3.0e30f, -3.0e30f, -3.0e30f, -3.0e30f};
    #pragma unroll
    for (int jt = 0; jt < 24; ++jt) {
        int j = jt * 16 + lr;
        int sp = srow0 - NW + j;
        bool pok = (sp >= 0) && (sp < NS);
        #pragma unroll
        for (int i = 0; i < 4; ++i) {
            int t = t0 + (g << 2) + i;
            bool ok = pok && (j >= t) && (j <= t + 2 * NW);
            float v = ok ? sc[jt][i] : -3.0e30f;
            sc[jt][i] = v;
            mx[i] = fmaxf(mx[i], v);
        }
    }
    #pragma unroll
    for (int m = 1; m < 16; m <<= 1) {
        #pragma unroll
        for (int i = 0; i < 4; ++i)
            mx[i] = fmaxf(mx[i], __shfl_xor(mx[i], m, 64));
    }
    float sm[4] = {0.f, 0.f, 0.f, 0.f};
    #pragma unroll
    for (int jt = 0; jt < 24; ++jt) {
        #pragma unroll
        for (int i = 0; i < 4; ++i) {
            float v = sc[jt][i];
            float p = (v > -1.0e30f) ? __expf(v - mx[i]) : 0.0f;
            sc[jt][i] = p;
            sm[i] += p;
        }
    }
    #pragma unroll
    for (int m = 1; m < 16; m <<= 1) {
        #pragma unroll
        for (int i = 0; i < 4; ++i)
            sm[i] += __shfl_xor(sm[i], m, 64);
    }
    float inv[4];
    #pragma unroll
    for (int i = 0; i < 4; ++i) inv[i] = 1.0f / sm[i];

    // write normalized P (bf16) to LDS
    #pragma unroll
    for (int jt = 0; jt < 24; ++jt) {
        #pragma unroll
        for (int i = 0; i < 4; ++i)
            pl[(t0 + (g << 2) + i) * PLD + jt * 16 + lr] = f2bf(sc[jt][i] * inv[i]);
    }

    __syncthreads();   // all K reads + P writes done

    // stage Vt [64 hd rows][384 j cols] over K's LDS region, zero-fill OOB
    #pragma unroll
    for (int it = 0; it < 6; ++it) {
        int idx = it * 512 + tid;
        int hd = idx / 48;
        int c = (idx % 48) << 3;
        int s0 = srow0 - NW + c;
        bf16x8 v = {};
        if (s0 >= 0 && s0 < NS)
            v = *(const bf16x8*)&vtg[(bh * NHD + hd) * NS + s0];
        *(bf16x8*)&kv[hd * PLD + c] = v;
    }
    __syncthreads();

    // PV: 16 rows x 64 cols, K = 384
    f32x4 o[4];
    #pragma unroll
    for (int nt = 0; nt < 4; ++nt) o[nt] = (f32x4){0.f, 0.f, 0.f, 0.f};
    #pragma unroll
    for (int kt = 0; kt < 12; ++kt) {
        bf16x8 ap = *(const bf16x8*)&pl[(t0 + lr) * PLD + (kt << 5) + (g << 3)];
        #pragma unroll
        for (int nt = 0; nt < 4; ++nt) {
            bf16x8 bv = *(const bf16x8*)&kv[(nt * 16 + lr) * PLD + (kt << 5) + (g << 3)];
            o[nt] = __builtin_amdgcn_mfma_f32_16x16x32_bf16(ap, bv, o[nt], 0, 0, 0);
        }
    }

    // x = src + context
    #pragma unroll
    for (int nt = 0; nt < 4; ++nt) {
        int d = nt * 16 + lr;
        int dcol = h * NHD + d;
        #pragma unroll
        for (int i = 0; i < 4; ++i) {
            int t = t0 + (g << 2) + i;
            long row = (long)b * NS + srow0 + t;
            float v = o[nt][i] + src[row * ND + dcol];
            x[row * ND + dcol] = v;
            xb[row * ND + dcol] = f2bf(v);
        }
    }

    // attn_w: this wave's 16 rows, 257 cols each: attw[t][c] = P[t][t+c]
    long aw = (bh * NS + srow0) * 257;
    for (int t = t0; t < t0 + 16; ++t) {
        long rowbase = aw + (long)t * 257;
        int pb = t * PLD + t;
        for (int c = lane; c < 257; c += 64)
            attw[rowbase + c] = bf2f(pl[pb + c]);
    }
}

// ---------------- layernorm (in-place on y) ----------------
__global__ __launch_bounds__(256) void ln_kernel(float* __restrict__ y,
                                                 const float* __restrict__ g2,
                                                 const float* __restrict__ beta2) {
    int row = blockIdx.x;
    long base = (long)row * ND;
    int tid = threadIdx.x;
    float v[3];
    float s = 0.f, ss = 0.f;
    #pragma unroll
    for (int i = 0; i < 3; ++i) {
        v[i] = y[base + i * 256 + tid];
        s += v[i];
        ss += v[i] * v[i];
    }
    #pragma unroll
    for (int m = 1; m < 64; m <<= 1) {
        s += __shfl_xor(s, m, 64);
        ss += __shfl_xor(ss, m, 64);
    }
    __shared__ float red[8];
    int wid = tid >> 6, lane = tid & 63;
    if (lane == 0) { red[wid] = s; red[wid + 4] = ss; }
    __syncthreads();
    s = red[0] + red[1] + red[2] + red[3];
    ss = red[4] + red[5] + red[6] + red[7];
    float mu = s * (1.0f / ND);
    float var = ss * (1.0f / ND) - mu * mu;
    float rstd = rsqrtf(var + 1e-6f);
    #pragma unroll
    for (int i = 0; i < 3; ++i) {
        int c = i * 256 + tid;
        y[base + c] = g2[c] * (v[i] - mu) * rstd + beta2[c];
    }
}

extern "C" void kernel_launch(void* const* d_in, const int* in_sizes, int n_in,
                              void* d_out, int out_size, void* d_ws, size_t ws_size,
                              hipStream_t stream) {
    const float* src  = (const float*)d_in[0];
    const float* Wq   = (const float*)d_in[1];
    const float* bq   = (const float*)d_in[2];
    const float* Wk   = (const float*)d_in[3];
    const float* bk   = (const float*)d_in[4];
    const float* Wv   = (const float*)d_in[5];
    const float* bv   = (const float*)d_in[6];
    const float* W1   = (const float*)d_in[7];
    const float* b1   = (const float*)d_in[8];
    const float* W2   = (const float*)d_in[9];
    const float* b2   = (const float*)d_in[10];
    const float* g2   = (const float*)d_in[11];
    const float* bt2  = (const float*)d_in[12];

    float* out  = (float*)d_out;                       // y, then LN result in-place
    float* attw = out + (long)NB * NS * ND;

    char* ws = (char*)d_ws;
    const size_t SZ_XF  = (size_t)NB * NS * ND * 4;    // 25165824
    const size_t SZ_XB  = (size_t)NB * NS * ND * 2;    // 12582912
    const size_t SZ_W1T = (size_t)ND * NDFF * 2;       // 4718592
    const size_t SZ_W2T = (size_t)NDFF * ND * 2;       // 4718592
    const size_t SZ_QKV = (size_t)NB * NS * ND * 2;    // 12582912 each
    const size_t SZ_WT  = (size_t)ND * ND * 2;         // 1179648 each

    float* x_f32 = (float*)ws;
    short* x_bf  = (short*)(ws + SZ_XF);
    short* W1T   = (short*)(ws + SZ_XF + SZ_XB);
    short* W2T   = (short*)(ws + SZ_XF + SZ_XB + SZ_W1T);
    char*  regA  = ws + SZ_XF + SZ_XB + SZ_W1T + SZ_W2T;
    short* srcb  = (short*)regA;
    short* WqT   = (short*)(regA + SZ_QKV);
    short* WkT   = (short*)(regA + SZ_QKV + SZ_WT);
    short* WvT   = (short*)(regA + SZ_QKV + 2 * SZ_WT);
    short* qb    = (short*)(regA + SZ_QKV + 3 * SZ_WT);
    short* kb_   = (short*)(regA + 2 * SZ_QKV + 3 * SZ_WT);
    short* vb_   = (short*)(regA + 3 * SZ_QKV + 3 * SZ_WT);
    short* hbuf  = (short*)regA;   // aliases srcb..vb_ (dead after attention)

    const int M = NB * NS;   // 8192

    // casts / transposes
    cast_bf16<<<(M * ND / 4 + 255) / 256, 256, 0, stream>>>(src, srcb, M * ND / 4);
    transpose_cast<<<dim3(ND / 32, ND / 32), 256, 0, stream>>>(Wq, WqT, ND, ND);
    transpose_cast<<<dim3(ND / 32, ND / 32), 256, 0, stream>>>(Wk, WkT, ND, ND);
    transpose_cast<<<dim3(ND / 32, ND / 32), 256, 0, stream>>>(Wv, WvT, ND, ND);
    transpose_cast<<<dim3(NDFF / 32, ND / 32), 256, 0, stream>>>(W1, W1T, ND, NDFF);
    transpose_cast<<<dim3(ND / 32, NDFF / 32), 256, 0, stream>>>(W2, W2T, NDFF, ND);

    // QKV projections
    gemm_bt<0><<<dim3(ND / 128, M / 128), 256, 0, stream>>>(srcb, WqT, bq, 0.125f, qb, nullptr, M, ND, ND);
    gemm_bt<0><<<dim3(ND / 128, M / 128), 256, 0, stream>>>(srcb, WkT, bk, 1.0f, kb_, nullptr, M, ND, ND);
    gemm_bt<1><<<dim3(ND / 128, M / 128), 256, 0, stream>>>(srcb, WvT, bv, 1.0f, vb_, nullptr, M, ND, ND);

    // band attention
    (void)hipFuncSetAttribute((const void*)attn_kernel,
                              hipFuncAttributeMaxDynamicSharedMemorySize, ATT_LDS);
    attn_kernel<<<NB * NH * NCH, 512, ATT_LDS, stream>>>(qb, kb_, vb_, src, attw, x_f32, x_bf);

    // FFN
    gemm_bt<2><<<dim3(NDFF / 128, M / 128), 256, 0, stream>>>(x_bf, W1T, b1, 1.0f, hbuf, nullptr, M, NDFF, ND);
    gemm_bt<3><<<dim3(ND / 128, M / 128), 256, 0, stream>>>(hbuf, W2T, b2, 1.0f, out, x_f32, M, ND, NDFF);

    // LayerNorm in-place
    ln_kernel<<<M, 256, 0, stream>>>(out, g2, bt2);
}

// Round 3
// 312.234 us; speedup vs baseline: 1.0278x; 1.0278x over previous
//
#include <hip/hip_runtime.h>
#include <hip/hip_bf16.h>
#include <stdint.h>

#define NB 2
#define NS 4096
#define ND 768
#define NH 12
#define NW 128
#define NDFF 3072
#define NHD 64
#define NCH 32   // NS/NW

typedef __attribute__((ext_vector_type(8))) short bf16x8;
typedef __attribute__((ext_vector_type(4))) short s16x4;
typedef __attribute__((ext_vector_type(4))) float f32x4;

__device__ __forceinline__ float bf2f(short u) {
    union { unsigned int i; float f; } c;
    c.i = ((unsigned int)(unsigned short)u) << 16;
    return c.f;
}
__device__ __forceinline__ short f2bf(float f) {
    union { float f; unsigned int i; } c;
    c.f = f;
    unsigned int x = c.i;
    return (short)((x + 0x7fffu + ((x >> 16) & 1u)) >> 16);
}

__device__ __forceinline__ void gl16(const void* g, const void* l) {
    __builtin_amdgcn_global_load_lds(
        (const __attribute__((address_space(1))) void*)g,
        (__attribute__((address_space(3))) void*)l, 16, 0, 0);
}

// ---------------- cast f32 -> bf16 (vectorized) ----------------
__global__ __launch_bounds__(256) void cast_bf16(const float* __restrict__ in,
                                                 short* __restrict__ out, int n4) {
    int i = blockIdx.x * 256 + threadIdx.x;
    if (i < n4) {
        f32x4 v = ((const f32x4*)in)[i];
        s16x4 o;
        o[0] = f2bf(v[0]); o[1] = f2bf(v[1]); o[2] = f2bf(v[2]); o[3] = f2bf(v[3]);
        ((s16x4*)out)[i] = o;
    }
}

// ---------------- transpose + cast: in[K][N] f32 -> out[N][K] bf16 ----------------
__global__ __launch_bounds__(256) void transpose_cast(const float* __restrict__ in,
                                                      short* __restrict__ out,
                                                      int K, int N) {
    __shared__ float tile[32][33];
    int kb = blockIdx.y * 32, nb = blockIdx.x * 32;
    int tx = threadIdx.x & 31, ty = threadIdx.x >> 5;   // ty 0..7
    #pragma unroll
    for (int r = ty; r < 32; r += 8)
        tile[r][tx] = in[(long)(kb + r) * N + nb + tx];
    __syncthreads();
    #pragma unroll
    for (int r = ty; r < 32; r += 8)
        out[(long)(nb + r) * K + kb + tx] = f2bf(tile[tx][r]);
}

// ---------------- 256x256 8-wave pipelined GEMM: C = A[M][K] @ Bt[N][K]^T ----------------
// BK=32, 4-deep LDS ring buffer (4 x 32KB), counted vmcnt(8) steady state,
// raw s_barrier (no drains), setprio around MFMA, XOR slot-swizzle on both
// staging source and ds_read (involution; conflict-free b128 reads).
// MODE 4: fused QKV epilogue (q scaled+BHSD, k BHSD, v BHDS)
// MODE 2: relu(acc+bias) -> bf16 [M][NDFF]
// MODE 3: acc+bias+xres  -> f32  [M][ND]
template<int MODE>
__global__ __launch_bounds__(512, 2) void gemm8(
    const short* __restrict__ A,
    const short* __restrict__ Bt,
    const float* __restrict__ b0,
    const float* __restrict__ b1,
    const float* __restrict__ b2,
    void* __restrict__ outp,
    const float* __restrict__ xres,
    int M, int N, int K)
{
    extern __shared__ char smem[];   // 4 bufs x (A 16KB + B 16KB) = 131072 B
    const int KT = K >> 5;
    int n0 = blockIdx.x * 256, m0 = blockIdx.y * 256;
    int tid = threadIdx.x;
    int wid = tid >> 6, lane = tid & 63;
    int wm = wid >> 2, wn = wid & 3;          // 2M x 4N waves; wave tile 128x64
    int g = lane >> 4, lr = lane & 15;

    // ---- staging geometry: per K-tile, A = 2 insts (8KB each), B = 2 insts.
    // lane covers LDS row Rs(+128 for inst1), slot lane&3; global k pre-swizzled.
    int Rs = wid * 16 + (lane >> 2);
    int soff = ((lane & 3) ^ ((lane >> 3) & 3)) << 3;   // swizzled k-element offset
    const short* gA0 = A + (long)(m0 + Rs) * K + soff;
    const short* gA1 = A + (long)(m0 + 128 + Rs) * K + soff;
    const short* gB0 = Bt + (long)(n0 + Rs) * K + soff;
    const short* gB1 = Bt + (long)(n0 + 128 + Rs) * K + soff;
    int ldsw = wid * 1024;                    // wave-uniform LDS sub-base

    // ---- fragment read addresses (swizzled slot, same involution)
    int aswz = (((lane >> 4) ^ ((lane >> 1) & 3)) & 3) << 4;
    int abase = (wm * 128 + lr) * 64 + aswz;           // + m*1024
    int bbase = 16384 + (wn * 64 + lr) * 64 + aswz;    // + n*1024

    f32x4 acc[8][4];
    #pragma unroll
    for (int m = 0; m < 8; ++m)
        #pragma unroll
        for (int n = 0; n < 4; ++n)
            acc[m][n] = (f32x4){0.f, 0.f, 0.f, 0.f};

    auto stgA = [&](int kt) {
        int off = (kt & 3) * 32768 + ldsw;
        long ko = (long)kt << 5;
        gl16(gA0 + ko, smem + off);
        gl16(gA1 + ko, smem + off + 8192);
    };
    auto stgB = [&](int kt) {
        int off = (kt & 3) * 32768 + 16384 + ldsw;
        long ko = (long)kt << 5;
        gl16(gB0 + ko, smem + off);
        gl16(gB1 + ko, smem + off + 8192);
    };

    // prologue: 3 K-tiles in flight, wait only for tile 0 (8 loads stay out)
    stgA(0); stgB(0); stgA(1); stgB(1); stgA(2); stgB(2);
    asm volatile("s_waitcnt vmcnt(8)" ::: "memory");
    __builtin_amdgcn_s_barrier();

    for (int kt = 0; kt < KT; ++kt) {
        const char* db = smem + (kt & 3) * 32768;
        bool pf = (kt + 3) < KT;
        // ---- phase 0: issue A-prefetch, read B frags + A frags m0..3, MFMA quadrant
        if (pf) stgA(kt + 3);
        bf16x8 bfr[4], af[4];
        #pragma unroll
        for (int n = 0; n < 4; ++n)
            bfr[n] = *(const bf16x8*)(db + bbase + n * 1024);
        #pragma unroll
        for (int m = 0; m < 4; ++m)
            af[m] = *(const bf16x8*)(db + abase + m * 1024);
        __builtin_amdgcn_s_barrier();
        asm volatile("s_waitcnt lgkmcnt(0)" ::: "memory");
        __builtin_amdgcn_s_setprio(1);
        #pragma unroll
        for (int m = 0; m < 4; ++m)
            #pragma unroll
            for (int n = 0; n < 4; ++n)
                acc[m][n] = __builtin_amdgcn_mfma_f32_16x16x32_bf16(
                    af[m], bfr[n], acc[m][n], 0, 0, 0);
        __builtin_amdgcn_s_setprio(0);
        __builtin_amdgcn_s_barrier();
        // ---- phase 1: issue B-prefetch, read A frags m4..7, MFMA quadrant
        if (pf) stgB(kt + 3);
        #pragma unroll
        for (int m = 0; m < 4; ++m)
            af[m] = *(const bf16x8*)(db + abase + (4 + m) * 1024);
        __builtin_amdgcn_s_barrier();
        asm volatile("s_waitcnt lgkmcnt(0)" ::: "memory");
        __builtin_amdgcn_s_setprio(1);
        #pragma unroll
        for (int m = 0; m < 4; ++m)
            #pragma unroll
            for (int n = 0; n < 4; ++n)
                acc[4 + m][n] = __builtin_amdgcn_mfma_f32_16x16x32_bf16(
                    af[m], bfr[n], acc[4 + m][n], 0, 0, 0);
        __builtin_amdgcn_s_setprio(0);
        // counted wait: tile kt+1 must be landed; keep 8 loads in flight
        if (kt + 3 < KT)      { asm volatile("s_waitcnt vmcnt(8)" ::: "memory"); }
        else if (kt + 2 < KT) { asm volatile("s_waitcnt vmcnt(4)" ::: "memory"); }
        else if (kt + 1 < KT) { asm volatile("s_waitcnt vmcnt(0)" ::: "memory"); }
        __builtin_amdgcn_s_barrier();
    }

    // ---- epilogue
    int mr0 = m0 + wm * 128;
    int nc0 = n0 + wn * 64;
    if (MODE == 4) {
        int proj = n0 / 768;   // 0=q,1=k,2=v (uniform: 768 = 3*256)
        const float* bp = (proj == 0) ? b0 : (proj == 1) ? b1 : b2;
        float scl = (proj == 0) ? 0.125f : 1.0f;
        short* obase = (short*)outp + (long)proj * ((long)NB * NS * ND);
        #pragma unroll
        for (int mt = 0; mt < 8; ++mt) {
            #pragma unroll
            for (int nt = 0; nt < 4; ++nt) {
                int c = nc0 + nt * 16 + lr - proj * 768;
                int hh = c >> 6, hd = c & 63;
                float bv = bp[c];
                if (proj == 2) {
                    int m = mr0 + mt * 16 + (g << 2);
                    int bbi = m >> 12, s = m & (NS - 1);
                    s16x4 ov;
                    ov[0] = f2bf(acc[mt][nt][0] + bv);
                    ov[1] = f2bf(acc[mt][nt][1] + bv);
                    ov[2] = f2bf(acc[mt][nt][2] + bv);
                    ov[3] = f2bf(acc[mt][nt][3] + bv);
                    *(s16x4*)&obase[((long)(bbi * NH + hh) * NHD + hd) * NS + s] = ov;
                } else {
                    #pragma unroll
                    for (int i = 0; i < 4; ++i) {
                        int m = mr0 + mt * 16 + (g << 2) + i;
                        int bbi = m >> 12, s = m & (NS - 1);
                        obase[((long)(bbi * NH + hh) * NS + s) * NHD + hd] =
                            f2bf((acc[mt][nt][i] + bv) * scl);
                    }
                }
            }
        }
    } else {
        #pragma unroll
        for (int mt = 0; mt < 8; ++mt) {
            #pragma unroll
            for (int nt = 0; nt < 4; ++nt) {
                int col = nc0 + nt * 16 + lr;
                float bv = b0[col];
                #pragma unroll
                for (int i = 0; i < 4; ++i) {
                    int m = mr0 + mt * 16 + (g << 2) + i;
                    float v = acc[mt][nt][i];
                    if (MODE == 2) {
                        v = fmaxf(v + bv, 0.f);
                        ((short*)outp)[(long)m * NDFF + col] = f2bf(v);
                    } else {
                        v = v + bv + xres[(long)m * ND + col];
                        ((float*)outp)[(long)m * ND + col] = v;
                    }
                }
            }
        }
    }
}

// ---------------- band attention ----------------
#define KLD 72    // 64 + 8 pad (bf16)
#define PLD 392   // 384 + 8 pad (bf16)
#define ATT_LDS (384 * KLD * 2 + 128 * PLD * 2)   // 55296 + 100352 = 155648 B

__global__ __launch_bounds__(512) void attn_kernel(
    const short* __restrict__ qg,   // (B,H,S,HD) bf16, pre-scaled
    const short* __restrict__ kg,   // (B,H,S,HD) bf16
    const short* __restrict__ vtg,  // (B,H,HD,S) bf16
    const float* __restrict__ src,  // (B,S,D) f32
    float* __restrict__ attw,       // (B,H,S,257) f32
    float* __restrict__ x,          // (B,S,D) f32
    short* __restrict__ xb)         // (B,S,D) bf16
{
    extern __shared__ char smem[];
    short* kv = (short*)smem;                     // K tile [384][KLD] then Vt [64][PLD]
    short* pl = (short*)(smem + 384 * KLD * 2);   // P [128][PLD], normalized probs

    int blk = blockIdx.x;
    int ch = blk & 31;
    int tmp = blk >> 5;
    int h = tmp % NH;
    int b = tmp / NH;
    int tid = threadIdx.x;
    int wid = tid >> 6;
    int lane = tid & 63;
    int g = lane >> 4, lr = lane & 15;
    long bh = (long)(b * NH + h);
    long kbase = bh * NS * NHD;
    int srow0 = ch * NW;

    // stage K rows j=0..383 (key pos = srow0-128+j), zero-fill OOB
    #pragma unroll
    for (int it = 0; it < 6; ++it) {
        int idx = it * 512 + tid;
        int j = idx >> 3;
        int c = (idx & 7) << 3;
        int s = srow0 - NW + j;
        bf16x8 v = {};
        if (s >= 0 && s < NS)
            v = *(const bf16x8*)&kg[kbase + (long)s * NHD + c];
        *(bf16x8*)&kv[j * KLD + c] = v;
    }

    // Q fragments for this wave's 16 rows
    int t0 = wid << 4;
    bf16x8 aq[2];
    #pragma unroll
    for (int kk = 0; kk < 2; ++kk)
        aq[kk] = *(const bf16x8*)&qg[kbase + (long)(srow0 + t0 + lr) * NHD + (kk << 5) + (g << 3)];

    __syncthreads();

    // scores: 24 col-tiles of 16, K=64
    f32x4 sc[24];
    #pragma unroll
    for (int jt = 0; jt < 24; ++jt) {
        f32x4 a = (f32x4){0.f, 0.f, 0.f, 0.f};
        #pragma unroll
        for (int kk = 0; kk < 2; ++kk) {
            bf16x8 bk = *(const bf16x8*)&kv[(jt * 16 + lr) * KLD + (kk << 5) + (g << 3)];
            a = __builtin_amdgcn_mfma_f32_16x16x32_bf16(aq[kk], bk, a, 0, 0, 0);
        }
        sc[jt] = a;
    }

    // mask + row max (rows of this lane: t = t0 + g*4 + i; col j = jt*16 + lr)
    float mx[4] = {-3.0e30f, -3.0e30f, -3.0e30f, -3.0e30f};
    #pragma unroll
    for (int jt = 0; jt < 24; ++jt) {
        int j = jt * 16 + lr;
        int sp = srow0 - NW + j;
        bool pok = (sp >= 0) && (sp < NS);
        #pragma unroll
        for (int i = 0; i < 4; ++i) {
            int t = t0 + (g << 2) + i;
            bool ok = pok && (j >= t) && (j <= t + 2 * NW);
            float v = ok ? sc[jt][i] : -3.0e30f;
            sc[jt][i] = v;
            mx[i] = fmaxf(mx[i], v);
        }
    }
    #pragma unroll
    for (int m = 1; m < 16; m <<= 1) {
        #pragma unroll
        for (int i = 0; i < 4; ++i)
            mx[i] = fmaxf(mx[i], __shfl_xor(mx[i], m, 64));
    }
    float sm[4] = {0.f, 0.f, 0.f, 0.f};
    #pragma unroll
    for (int jt = 0; jt < 24; ++jt) {
        #pragma unroll
        for (int i = 0; i < 4; ++i) {
            float v = sc[jt][i];
            float p = (v > -1.0e30f) ? __expf(v - mx[i]) : 0.0f;
            sc[jt][i] = p;
            sm[i] += p;
        }
    }
    #pragma unroll
    for (int m = 1; m < 16; m <<= 1) {
        #pragma unroll
        for (int i = 0; i < 4; ++i)
            sm[i] += __shfl_xor(sm[i], m, 64);
    }
    float inv[4];
    #pragma unroll
    for (int i = 0; i < 4; ++i) inv[i] = 1.0f / sm[i];

    // write normalized P (bf16) to LDS
    #pragma unroll
    for (int jt = 0; jt < 24; ++jt) {
        #pragma unroll
        for (int i = 0; i < 4; ++i)
            pl[(t0 + (g << 2) + i) * PLD + jt * 16 + lr] = f2bf(sc[jt][i] * inv[i]);
    }

    __syncthreads();   // all K reads + P writes done

    // stage Vt [64 hd rows][384 j cols] over K's LDS region, zero-fill OOB
    #pragma unroll
    for (int it = 0; it < 6; ++it) {
        int idx = it * 512 + tid;
        int hd = idx / 48;
        int c = (idx % 48) << 3;
        int s0 = srow0 - NW + c;
        bf16x8 v = {};
        if (s0 >= 0 && s0 < NS)
            v = *(const bf16x8*)&vtg[(bh * NHD + hd) * NS + s0];
        *(bf16x8*)&kv[hd * PLD + c] = v;
    }
    __syncthreads();

    // PV: 16 rows x 64 cols, K = 384
    f32x4 o[4];
    #pragma unroll
    for (int nt = 0; nt < 4; ++nt) o[nt] = (f32x4){0.f, 0.f, 0.f, 0.f};
    #pragma unroll
    for (int kt = 0; kt < 12; ++kt) {
        bf16x8 ap = *(const bf16x8*)&pl[(t0 + lr) * PLD + (kt << 5) + (g << 3)];
        #pragma unroll
        for (int nt = 0; nt < 4; ++nt) {
            bf16x8 bv = *(const bf16x8*)&kv[(nt * 16 + lr) * PLD + (kt << 5) + (g << 3)];
            o[nt] = __builtin_amdgcn_mfma_f32_16x16x32_bf16(ap, bv, o[nt], 0, 0, 0);
        }
    }

    // x = src + context
    #pragma unroll
    for (int nt = 0; nt < 4; ++nt) {
        int d = nt * 16 + lr;
        int dcol = h * NHD + d;
        #pragma unroll
        for (int i = 0; i < 4; ++i) {
            int t = t0 + (g << 2) + i;
            long row = (long)b * NS + srow0 + t;
            float v = o[nt][i] + src[row * ND + dcol];
            x[row * ND + dcol] = v;
            xb[row * ND + dcol] = f2bf(v);
        }
    }

    // attn_w: this wave's 16 rows, 257 cols each: attw[t][c] = P[t][t+c]
    long aw = (bh * NS + srow0) * 257;
    for (int t = t0; t < t0 + 16; ++t) {
        long rowbase = aw + (long)t * 257;
        int pb = t * PLD + t;
        for (int c = lane; c < 257; c += 64)
            attw[rowbase + c] = bf2f(pl[pb + c]);
    }
}

// ---------------- layernorm (in-place on y) ----------------
__global__ __launch_bounds__(256) void ln_kernel(float* __restrict__ y,
                                                 const float* __restrict__ g2,
                                                 const float* __restrict__ beta2) {
    int row = blockIdx.x;
    long base = (long)row * ND;
    int tid = threadIdx.x;
    float v[3];
    float s = 0.f, ss = 0.f;
    #pragma unroll
    for (int i = 0; i < 3; ++i) {
        v[i] = y[base + i * 256 + tid];
        s += v[i];
        ss += v[i] * v[i];
    }
    #pragma unroll
    for (int m = 1; m < 64; m <<= 1) {
        s += __shfl_xor(s, m, 64);
        ss += __shfl_xor(ss, m, 64);
    }
    __shared__ float red[8];
    int wid = tid >> 6, lane = tid & 63;
    if (lane == 0) { red[wid] = s; red[wid + 4] = ss; }
    __syncthreads();
    s = red[0] + red[1] + red[2] + red[3];
    ss = red[4] + red[5] + red[6] + red[7];
    float mu = s * (1.0f / ND);
    float var = ss * (1.0f / ND) - mu * mu;
    float rstd = rsqrtf(var + 1e-6f);
    #pragma unroll
    for (int i = 0; i < 3; ++i) {
        int c = i * 256 + tid;
        y[base + c] = g2[c] * (v[i] - mu) * rstd + beta2[c];
    }
}

extern "C" void kernel_launch(void* const* d_in, const int* in_sizes, int n_in,
                              void* d_out, int out_size, void* d_ws, size_t ws_size,
                              hipStream_t stream) {
    const float* src  = (const float*)d_in[0];
    const float* Wq   = (const float*)d_in[1];
    const float* bq   = (const float*)d_in[2];
    const float* Wk   = (const float*)d_in[3];
    const float* bk   = (const float*)d_in[4];
    const float* Wv   = (const float*)d_in[5];
    const float* bv   = (const float*)d_in[6];
    const float* W1   = (const float*)d_in[7];
    const float* b1   = (const float*)d_in[8];
    const float* W2   = (const float*)d_in[9];
    const float* b2   = (const float*)d_in[10];
    const float* g2   = (const float*)d_in[11];
    const float* bt2  = (const float*)d_in[12];

    float* out  = (float*)d_out;                       // y, then LN result in-place
    float* attw = out + (long)NB * NS * ND;

    char* ws = (char*)d_ws;
    const size_t SZ_XF  = (size_t)NB * NS * ND * 4;    // 25165824
    const size_t SZ_XB  = (size_t)NB * NS * ND * 2;    // 12582912
    const size_t SZ_W1T = (size_t)ND * NDFF * 2;       // 4718592
    const size_t SZ_W2T = (size_t)NDFF * ND * 2;       // 4718592
    const size_t SZ_QKV = (size_t)NB * NS * ND * 2;    // 12582912 each
    const size_t SZ_WT  = (size_t)ND * ND * 2;         // 1179648 each

    float* x_f32 = (float*)ws;
    short* x_bf  = (short*)(ws + SZ_XF);
    short* W1T   = (short*)(ws + SZ_XF + SZ_XB);
    short* W2T   = (short*)(ws + SZ_XF + SZ_XB + SZ_W1T);
    char*  regA  = ws + SZ_XF + SZ_XB + SZ_W1T + SZ_W2T;
    short* srcb  = (short*)regA;
    short* WqT   = (short*)(regA + SZ_QKV);            // rows 0..767   }  contiguous
    short* WkT   = (short*)(regA + SZ_QKV + SZ_WT);    // rows 768..1535}  Wqkv^T
    short* WvT   = (short*)(regA + SZ_QKV + 2 * SZ_WT);// rows 1536..2303} [2304][768]
    short* qb    = (short*)(regA + SZ_QKV + 3 * SZ_WT);
    short* kb_   = (short*)(regA + 2 * SZ_QKV + 3 * SZ_WT);
    short* vb_   = (short*)(regA + 3 * SZ_QKV + 3 * SZ_WT);
    short* hbuf  = (short*)regA;   // aliases srcb..vb_ (dead after attention)

    const int M = NB * NS;   // 8192

    // casts / transposes
    cast_bf16<<<(M * ND / 4 + 255) / 256, 256, 0, stream>>>(src, srcb, M * ND / 4);
    transpose_cast<<<dim3(ND / 32, ND / 32), 256, 0, stream>>>(Wq, WqT, ND, ND);
    transpose_cast<<<dim3(ND / 32, ND / 32), 256, 0, stream>>>(Wk, WkT, ND, ND);
    transpose_cast<<<dim3(ND / 32, ND / 32), 256, 0, stream>>>(Wv, WvT, ND, ND);
    transpose_cast<<<dim3(NDFF / 32, ND / 32), 256, 0, stream>>>(W1, W1T, ND, NDFF);
    transpose_cast<<<dim3(ND / 32, NDFF / 32), 256, 0, stream>>>(W2, W2T, NDFF, ND);

    (void)hipFuncSetAttribute(reinterpret_cast<const void*>(gemm8<4>),
                              hipFuncAttributeMaxDynamicSharedMemorySize, 131072);
    (void)hipFuncSetAttribute(reinterpret_cast<const void*>(gemm8<2>),
                              hipFuncAttributeMaxDynamicSharedMemorySize, 131072);
    (void)hipFuncSetAttribute(reinterpret_cast<const void*>(gemm8<3>),
                              hipFuncAttributeMaxDynamicSharedMemorySize, 131072);

    // fused QKV projection (N = 2304 = q|k|v)
    gemm8<4><<<dim3(2304 / 256, M / 256), 512, 131072, stream>>>(
        srcb, WqT, bq, bk, bv, qb, nullptr, M, 2304, ND);

    // band attention
    (void)hipFuncSetAttribute(reinterpret_cast<const void*>(attn_kernel),
                              hipFuncAttributeMaxDynamicSharedMemorySize, ATT_LDS);
    attn_kernel<<<NB * NH * NCH, 512, ATT_LDS, stream>>>(qb, kb_, vb_, src, attw, x_f32, x_bf);

    // FFN
    gemm8<2><<<dim3(NDFF / 256, M / 256), 512, 131072, stream>>>(
        x_bf, W1T, b1, b1, b1, hbuf, nullptr, M, NDFF, ND);
    gemm8<3><<<dim3(ND / 256, M / 256), 512, 131072, stream>>>(
        hbuf, W2T, b2, b2, b2, out, x_f32, M, ND, NDFF);

    // LayerNorm in-place
    ln_kernel<<<M, 256, 0, stream>>>(out, g2, bt2);
}

// Round 4
// 257.488 us; speedup vs baseline: 1.2463x; 1.2126x over previous
//
#include <hip/hip_runtime.h>
#include <hip/hip_bf16.h>
#include <stdint.h>

#define NB 2
#define NS 4096
#define ND 768
#define NH 12
#define NW 128
#define NDFF 3072
#define NHD 64
#define NCH 32   // NS/NW

typedef __attribute__((ext_vector_type(8))) short bf16x8;
typedef __attribute__((ext_vector_type(4))) short s16x4;
typedef __attribute__((ext_vector_type(4))) float f32x4;

__device__ __forceinline__ float bf2f(short u) {
    union { unsigned int i; float f; } c;
    c.i = ((unsigned int)(unsigned short)u) << 16;
    return c.f;
}
__device__ __forceinline__ short f2bf(float f) {
    union { float f; unsigned int i; } c;
    c.f = f;
    unsigned int x = c.i;
    return (short)((x + 0x7fffu + ((x >> 16) & 1u)) >> 16);
}

__device__ __forceinline__ void gl16(const void* g, const void* l) {
    __builtin_amdgcn_global_load_lds(
        (const __attribute__((address_space(1))) void*)g,
        (__attribute__((address_space(3))) void*)l, 16, 0, 0);
}

// ---------------- cast f32 -> bf16 (vectorized) ----------------
__global__ __launch_bounds__(256) void cast_bf16(const float* __restrict__ in,
                                                 short* __restrict__ out, int n4) {
    int i = blockIdx.x * 256 + threadIdx.x;
    if (i < n4) {
        f32x4 v = ((const f32x4*)in)[i];
        s16x4 o;
        o[0] = f2bf(v[0]); o[1] = f2bf(v[1]); o[2] = f2bf(v[2]); o[3] = f2bf(v[3]);
        ((s16x4*)out)[i] = o;
    }
}

// ---------------- transpose + cast: in[K][N] f32 -> out[N][K] bf16 ----------------
__global__ __launch_bounds__(256) void transpose_cast(const float* __restrict__ in,
                                                      short* __restrict__ out,
                                                      int K, int N) {
    __shared__ float tile[32][33];
    int kb = blockIdx.y * 32, nb = blockIdx.x * 32;
    int tx = threadIdx.x & 31, ty = threadIdx.x >> 5;   // ty 0..7
    #pragma unroll
    for (int r = ty; r < 32; r += 8)
        tile[r][tx] = in[(long)(kb + r) * N + nb + tx];
    __syncthreads();
    #pragma unroll
    for (int r = ty; r < 32; r += 8)
        out[(long)(nb + r) * K + kb + tx] = f2bf(tile[tx][r]);
}

// ------------- 128x128 double-buffered GEMM: C = A[M][K] @ Bt[N][K]^T -------------
// BK=64, 2-deep LDS dbuf (64KB -> 2 blocks/CU), gl16 staging with XOR slot-swizzle
// (both-sides involution: pre-swizzled global src + swizzled ds_read), ONE raw
// barrier per K-tile: stage(t+1) issued BEFORE compute(t), vmcnt(0) after.
// XCD-aware tile swizzle (grid % 8 == 0 for all our shapes).
// MODE 4: fused QKV epilogue (q scaled+BHSD, k BHSD, v BHDS)
// MODE 2: relu(acc+bias) -> bf16 [M][NDFF]
// MODE 3: acc+bias+xres  -> f32  [M][ND]
template<int MODE>
__global__ __launch_bounds__(256, 2) void gemmdb(
    const short* __restrict__ A,
    const short* __restrict__ Bt,
    const float* __restrict__ b0,
    const float* __restrict__ b1,
    const float* __restrict__ b2,
    void* __restrict__ outp,
    const float* __restrict__ xres,
    int M, int N, int K, int gx)
{
    __shared__ short lds[2][256 * 64];   // per buf: A[128][64] | B[128][64]
    const int KT = K >> 6;

    // XCD-aware swizzle: XCD x gets contiguous tile chunk (nwg % 8 == 0)
    int cpx = gridDim.x >> 3;
    int bid = blockIdx.x;
    int tile = (bid & 7) * cpx + (bid >> 3);
    int n0 = (tile % gx) * 128;
    int m0 = (tile / gx) * 128;

    int tid = threadIdx.x;
    int wid = tid >> 6, lane = tid & 63;
    int wr = wid >> 1, wc = wid & 1;          // 2x2 waves, wave tile 64x64
    int g = lane >> 4, lr = lane & 15;

    // staging: per K-tile A=16KB, B=16KB; per wave 4 gl16 each (1KB chunks of 8 rows).
    // lane l -> row chunkrow + (l>>3), phys slot l&7; global k pre-swizzled so that
    // phys slot s of row r holds logical k-slot s ^ (r&7).
    int rl = lane >> 3, sl = lane & 7;
    int soff = (sl ^ rl) << 3;                 // k-element offset (swizzled)
    const short* gA[4];
    const short* gB[4];
    #pragma unroll
    for (int c = 0; c < 4; ++c) {
        int row = c * 32 + wid * 8 + rl;
        gA[c] = A + (long)(m0 + row) * K + soff;
        gB[c] = Bt + (long)(n0 + row) * K + soff;
    }

    f32x4 acc[4][4];
    #pragma unroll
    for (int a = 0; a < 4; ++a)
        #pragma unroll
        for (int c = 0; c < 4; ++c)
            acc[a][c] = (f32x4){0.f, 0.f, 0.f, 0.f};

    auto stage = [&](int t, int buf) {
        long ko = (long)t << 6;
        #pragma unroll
        for (int c = 0; c < 4; ++c) {
            int lbase = (c * 32 + wid * 8) * 64;
            gl16(gA[c] + ko, &lds[buf][lbase]);
            gl16(gB[c] + ko, &lds[buf][128 * 64 + lbase]);
        }
    };

    stage(0, 0);
    asm volatile("s_waitcnt vmcnt(0)" ::: "memory");
    __builtin_amdgcn_s_barrier();

    int buf = 0;
    for (int t = 0; t < KT; ++t) {
        if (t + 1 < KT) stage(t + 1, buf ^ 1);
        const short* bufA = lds[buf];
        const short* bufB = lds[buf] + 128 * 64;
        bf16x8 af[2][4], bfr[2][4];
        #pragma unroll
        for (int kk = 0; kk < 2; ++kk) {
            int ph = (((kk << 2) + g) ^ (lr & 7)) << 3;   // swizzled k-slot (elems)
            #pragma unroll
            for (int mt = 0; mt < 4; ++mt)
                af[kk][mt] = *(const bf16x8*)&bufA[(wr * 64 + mt * 16 + lr) * 64 + ph];
            #pragma unroll
            for (int nt = 0; nt < 4; ++nt)
                bfr[kk][nt] = *(const bf16x8*)&bufB[(wc * 64 + nt * 16 + lr) * 64 + ph];
        }
        #pragma unroll
        for (int kk = 0; kk < 2; ++kk)
            #pragma unroll
            for (int mt = 0; mt < 4; ++mt)
                #pragma unroll
                for (int nt = 0; nt < 4; ++nt)
                    acc[mt][nt] = __builtin_amdgcn_mfma_f32_16x16x32_bf16(
                        af[kk][mt], bfr[kk][nt], acc[mt][nt], 0, 0, 0);
        asm volatile("s_waitcnt vmcnt(0)" ::: "memory");
        __builtin_amdgcn_s_barrier();
        buf ^= 1;
    }

    // ---- epilogue
    int mr0 = m0 + wr * 64;
    int nc0 = n0 + wc * 64;
    if (MODE == 4) {
        int proj = n0 / 768;   // 0=q,1=k,2=v (block never straddles: 768 % 128 == 0)
        const float* bp = (proj == 0) ? b0 : (proj == 1) ? b1 : b2;
        float scl = (proj == 0) ? 0.125f : 1.0f;
        short* obase = (short*)outp + (long)proj * ((long)NB * NS * ND);
        #pragma unroll
        for (int mt = 0; mt < 4; ++mt) {
            #pragma unroll
            for (int nt = 0; nt < 4; ++nt) {
                int c = nc0 + nt * 16 + lr - proj * 768;
                int hh = c >> 6, hd = c & 63;
                float bv = bp[c];
                if (proj == 2) {
                    int m = mr0 + mt * 16 + (g << 2);
                    int bbi = m >> 12, s = m & (NS - 1);
                    s16x4 ov;
                    ov[0] = f2bf(acc[mt][nt][0] + bv);
                    ov[1] = f2bf(acc[mt][nt][1] + bv);
                    ov[2] = f2bf(acc[mt][nt][2] + bv);
                    ov[3] = f2bf(acc[mt][nt][3] + bv);
                    *(s16x4*)&obase[((long)(bbi * NH + hh) * NHD + hd) * NS + s] = ov;
                } else {
                    #pragma unroll
                    for (int i = 0; i < 4; ++i) {
                        int m = mr0 + mt * 16 + (g << 2) + i;
                        int bbi = m >> 12, s = m & (NS - 1);
                        obase[((long)(bbi * NH + hh) * NS + s) * NHD + hd] =
                            f2bf((acc[mt][nt][i] + bv) * scl);
                    }
                }
            }
        }
    } else {
        #pragma unroll
        for (int mt = 0; mt < 4; ++mt) {
            #pragma unroll
            for (int nt = 0; nt < 4; ++nt) {
                int col = nc0 + nt * 16 + lr;
                float bv = b0[col];
                #pragma unroll
                for (int i = 0; i < 4; ++i) {
                    int m = mr0 + mt * 16 + (g << 2) + i;
                    float v = acc[mt][nt][i];
                    if (MODE == 2) {
                        v = fmaxf(v + bv, 0.f);
                        ((short*)outp)[(long)m * NDFF + col] = f2bf(v);
                    } else {
                        v = v + bv + xres[(long)m * ND + col];
                        ((float*)outp)[(long)m * ND + col] = v;
                    }
                }
            }
        }
    }
}

// ---------------- band attention ----------------
#define KLD 72    // 64 + 8 pad (bf16)
#define PLD 392   // 384 + 8 pad (bf16)
#define ATT_LDS (384 * KLD * 2 + 128 * PLD * 2)   // 55296 + 100352 = 155648 B

__global__ __launch_bounds__(512) void attn_kernel(
    const short* __restrict__ qg,   // (B,H,S,HD) bf16, pre-scaled
    const short* __restrict__ kg,   // (B,H,S,HD) bf16
    const short* __restrict__ vtg,  // (B,H,HD,S) bf16
    const float* __restrict__ src,  // (B,S,D) f32
    float* __restrict__ attw,       // (B,H,S,257) f32
    float* __restrict__ x,          // (B,S,D) f32
    short* __restrict__ xb)         // (B,S,D) bf16
{
    extern __shared__ char smem[];
    short* kv = (short*)smem;                     // K tile [384][KLD] then Vt [64][PLD]
    short* pl = (short*)(smem + 384 * KLD * 2);   // P [128][PLD], normalized probs

    int blk = blockIdx.x;
    int ch = blk & 31;
    int tmp = blk >> 5;
    int h = tmp % NH;
    int b = tmp / NH;
    int tid = threadIdx.x;
    int wid = tid >> 6;
    int lane = tid & 63;
    int g = lane >> 4, lr = lane & 15;
    long bh = (long)(b * NH + h);
    long kbase = bh * NS * NHD;
    int srow0 = ch * NW;

    // stage K rows j=0..383 (key pos = srow0-128+j), zero-fill OOB
    #pragma unroll
    for (int it = 0; it < 6; ++it) {
        int idx = it * 512 + tid;
        int j = idx >> 3;
        int c = (idx & 7) << 3;
        int s = srow0 - NW + j;
        bf16x8 v = {};
        if (s >= 0 && s < NS)
            v = *(const bf16x8*)&kg[kbase + (long)s * NHD + c];
        *(bf16x8*)&kv[j * KLD + c] = v;
    }

    // Q fragments for this wave's 16 rows
    int t0 = wid << 4;
    bf16x8 aq[2];
    #pragma unroll
    for (int kk = 0; kk < 2; ++kk)
        aq[kk] = *(const bf16x8*)&qg[kbase + (long)(srow0 + t0 + lr) * NHD + (kk << 5) + (g << 3)];

    __syncthreads();

    // scores: 24 col-tiles of 16, K=64
    f32x4 sc[24];
    #pragma unroll
    for (int jt = 0; jt < 24; ++jt) {
        f32x4 a = (f32x4){0.f, 0.f, 0.f, 0.f};
        #pragma unroll
        for (int kk = 0; kk < 2; ++kk) {
            bf16x8 bk = *(const bf16x8*)&kv[(jt * 16 + lr) * KLD + (kk << 5) + (g << 3)];
            a = __builtin_amdgcn_mfma_f32_16x16x32_bf16(aq[kk], bk, a, 0, 0, 0);
        }
        sc[jt] = a;
    }

    // mask + row max (rows of this lane: t = t0 + g*4 + i; col j = jt*16 + lr)
    float mx[4] = {-3.0e30f, -3.0e30f, -3.0e30f, -3.0e30f};
    #pragma unroll
    for (int jt = 0; jt < 24; ++jt) {
        int j = jt * 16 + lr;
        int sp = srow0 - NW + j;
        bool pok = (sp >= 0) && (sp < NS);
        #pragma unroll
        for (int i = 0; i < 4; ++i) {
            int t = t0 + (g << 2) + i;
            bool ok = pok && (j >= t) && (j <= t + 2 * NW);
            float v = ok ? sc[jt][i] : -3.0e30f;
            sc[jt][i] = v;
            mx[i] = fmaxf(mx[i], v);
        }
    }
    #pragma unroll
    for (int m = 1; m < 16; m <<= 1) {
        #pragma unroll
        for (int i = 0; i < 4; ++i)
            mx[i] = fmaxf(mx[i], __shfl_xor(mx[i], m, 64));
    }
    float sm[4] = {0.f, 0.f, 0.f, 0.f};
    #pragma unroll
    for (int jt = 0; jt < 24; ++jt) {
        #pragma unroll
        for (int i = 0; i < 4; ++i) {
            float v = sc[jt][i];
            float p = (v > -1.0e30f) ? __expf(v - mx[i]) : 0.0f;
            sc[jt][i] = p;
            sm[i] += p;
        }
    }
    #pragma unroll
    for (int m = 1; m < 16; m <<= 1) {
        #pragma unroll
        for (int i = 0; i < 4; ++i)
            sm[i] += __shfl_xor(sm[i], m, 64);
    }
    float inv[4];
    #pragma unroll
    for (int i = 0; i < 4; ++i) inv[i] = 1.0f / sm[i];

    // write normalized P (bf16) to LDS
    #pragma unroll
    for (int jt = 0; jt < 24; ++jt) {
        #pragma unroll
        for (int i = 0; i < 4; ++i)
            pl[(t0 + (g << 2) + i) * PLD + jt * 16 + lr] = f2bf(sc[jt][i] * inv[i]);
    }

    __syncthreads();   // all K reads + P writes done

    // stage Vt [64 hd rows][384 j cols] over K's LDS region, zero-fill OOB
    #pragma unroll
    for (int it = 0; it < 6; ++it) {
        int idx = it * 512 + tid;
        int hd = idx / 48;
        int c = (idx % 48) << 3;
        int s0 = srow0 - NW + c;
        bf16x8 v = {};
        if (s0 >= 0 && s0 < NS)
            v = *(const bf16x8*)&vtg[(bh * NHD + hd) * NS + s0];
        *(bf16x8*)&kv[hd * PLD + c] = v;
    }
    __syncthreads();

    // PV: 16 rows x 64 cols, K = 384
    f32x4 o[4];
    #pragma unroll
    for (int nt = 0; nt < 4; ++nt) o[nt] = (f32x4){0.f, 0.f, 0.f, 0.f};
    #pragma unroll
    for (int kt = 0; kt < 12; ++kt) {
        bf16x8 ap = *(const bf16x8*)&pl[(t0 + lr) * PLD + (kt << 5) + (g << 3)];
        #pragma unroll
        for (int nt = 0; nt < 4; ++nt) {
            bf16x8 bv = *(const bf16x8*)&kv[(nt * 16 + lr) * PLD + (kt << 5) + (g << 3)];
            o[nt] = __builtin_amdgcn_mfma_f32_16x16x32_bf16(ap, bv, o[nt], 0, 0, 0);
        }
    }

    // x = src + context
    #pragma unroll
    for (int nt = 0; nt < 4; ++nt) {
        int d = nt * 16 + lr;
        int dcol = h * NHD + d;
        #pragma unroll
        for (int i = 0; i < 4; ++i) {
            int t = t0 + (g << 2) + i;
            long row = (long)b * NS + srow0 + t;
            float v = o[nt][i] + src[row * ND + dcol];
            x[row * ND + dcol] = v;
            xb[row * ND + dcol] = f2bf(v);
        }
    }

    // attn_w: this wave's 16 rows, 257 cols each: attw[t][c] = P[t][t+c]
    long aw = (bh * NS + srow0) * 257;
    for (int t = t0; t < t0 + 16; ++t) {
        long rowbase = aw + (long)t * 257;
        int pb = t * PLD + t;
        for (int c = lane; c < 257; c += 64)
            attw[rowbase + c] = bf2f(pl[pb + c]);
    }
}

// ---------------- layernorm (in-place on y) ----------------
__global__ __launch_bounds__(256) void ln_kernel(float* __restrict__ y,
                                                 const float* __restrict__ g2,
                                                 const float* __restrict__ beta2) {
    int row = blockIdx.x;
    long base = (long)row * ND;
    int tid = threadIdx.x;
    float v[3];
    float s = 0.f, ss = 0.f;
    #pragma unroll
    for (int i = 0; i < 3; ++i) {
        v[i] = y[base + i * 256 + tid];
        s += v[i];
        ss += v[i] * v[i];
    }
    #pragma unroll
    for (int m = 1; m < 64; m <<= 1) {
        s += __shfl_xor(s, m, 64);
        ss += __shfl_xor(ss, m, 64);
    }
    __shared__ float red[8];
    int wid = tid >> 6, lane = tid & 63;
    if (lane == 0) { red[wid] = s; red[wid + 4] = ss; }
    __syncthreads();
    s = red[0] + red[1] + red[2] + red[3];
    ss = red[4] + red[5] + red[6] + red[7];
    float mu = s * (1.0f / ND);
    float var = ss * (1.0f / ND) - mu * mu;
    float rstd = rsqrtf(var + 1e-6f);
    #pragma unroll
    for (int i = 0; i < 3; ++i) {
        int c = i * 256 + tid;
        y[base + c] = g2[c] * (v[i] - mu) * rstd + beta2[c];
    }
}

extern "C" void kernel_launch(void* const* d_in, const int* in_sizes, int n_in,
                              void* d_out, int out_size, void* d_ws, size_t ws_size,
                              hipStream_t stream) {
    const float* src  = (const float*)d_in[0];
    const float* Wq   = (const float*)d_in[1];
    const float* bq   = (const float*)d_in[2];
    const float* Wk   = (const float*)d_in[3];
    const float* bk   = (const float*)d_in[4];
    const float* Wv   = (const float*)d_in[5];
    const float* bv   = (const float*)d_in[6];
    const float* W1   = (const float*)d_in[7];
    const float* b1   = (const float*)d_in[8];
    const float* W2   = (const float*)d_in[9];
    const float* b2   = (const float*)d_in[10];
    const float* g2   = (const float*)d_in[11];
    const float* bt2  = (const float*)d_in[12];

    float* out  = (float*)d_out;                       // y, then LN result in-place
    float* attw = out + (long)NB * NS * ND;

    char* ws = (char*)d_ws;
    const size_t SZ_XF  = (size_t)NB * NS * ND * 4;    // 25165824
    const size_t SZ_XB  = (size_t)NB * NS * ND * 2;    // 12582912
    const size_t SZ_W1T = (size_t)ND * NDFF * 2;       // 4718592
    const size_t SZ_W2T = (size_t)NDFF * ND * 2;       // 4718592
    const size_t SZ_QKV = (size_t)NB * NS * ND * 2;    // 12582912 each
    const size_t SZ_WT  = (size_t)ND * ND * 2;         // 1179648 each

    float* x_f32 = (float*)ws;
    short* x_bf  = (short*)(ws + SZ_XF);
    short* W1T   = (short*)(ws + SZ_XF + SZ_XB);
    short* W2T   = (short*)(ws + SZ_XF + SZ_XB + SZ_W1T);
    char*  regA  = ws + SZ_XF + SZ_XB + SZ_W1T + SZ_W2T;
    short* srcb  = (short*)regA;
    short* WqT   = (short*)(regA + SZ_QKV);            // rows 0..767   }  contiguous
    short* WkT   = (short*)(regA + SZ_QKV + SZ_WT);    // rows 768..1535}  Wqkv^T
    short* WvT   = (short*)(regA + SZ_QKV + 2 * SZ_WT);// rows 1536..2303} [2304][768]
    short* qb    = (short*)(regA + SZ_QKV + 3 * SZ_WT);
    short* kb_   = (short*)(regA + 2 * SZ_QKV + 3 * SZ_WT);
    short* vb_   = (short*)(regA + 3 * SZ_QKV + 3 * SZ_WT);
    short* hbuf  = (short*)regA;   // aliases srcb..vb_ (dead after attention)

    const int M = NB * NS;   // 8192

    // casts / transposes
    cast_bf16<<<(M * ND / 4 + 255) / 256, 256, 0, stream>>>(src, srcb, M * ND / 4);
    transpose_cast<<<dim3(ND / 32, ND / 32), 256, 0, stream>>>(Wq, WqT, ND, ND);
    transpose_cast<<<dim3(ND / 32, ND / 32), 256, 0, stream>>>(Wk, WkT, ND, ND);
    transpose_cast<<<dim3(ND / 32, ND / 32), 256, 0, stream>>>(Wv, WvT, ND, ND);
    transpose_cast<<<dim3(NDFF / 32, ND / 32), 256, 0, stream>>>(W1, W1T, ND, NDFF);
    transpose_cast<<<dim3(ND / 32, NDFF / 32), 256, 0, stream>>>(W2, W2T, NDFF, ND);

    // fused QKV projection (N = 2304 = q|k|v), grid 18*64 = 1152 (div by 8)
    gemmdb<4><<<(2304 / 128) * (M / 128), 256, 0, stream>>>(
        srcb, WqT, bq, bk, bv, qb, nullptr, M, 2304, ND, 2304 / 128);

    // band attention
    (void)hipFuncSetAttribute(reinterpret_cast<const void*>(attn_kernel),
                              hipFuncAttributeMaxDynamicSharedMemorySize, ATT_LDS);
    attn_kernel<<<NB * NH * NCH, 512, ATT_LDS, stream>>>(qb, kb_, vb_, src, attw, x_f32, x_bf);

    // FFN: grids 24*64 = 1536 and 6*64 = 384 (both div by 8)
    gemmdb<2><<<(NDFF / 128) * (M / 128), 256, 0, stream>>>(
        x_bf, W1T, b1, b1, b1, hbuf, nullptr, M, NDFF, ND, NDFF / 128);
    gemmdb<3><<<(ND / 128) * (M / 128), 256, 0, stream>>>(
        hbuf, W2T, b2, b2, b2, out, x_f32, M, ND, NDFF, ND / 128);

    // LayerNorm in-place
    ln_kernel<<<M, 256, 0, stream>>>(out, g2, bt2);
}

// Round 5
// 254.202 us; speedup vs baseline: 1.2624x; 1.0129x over previous
//
#include <hip/hip_runtime.h>
#include <hip/hip_bf16.h>
#include <stdint.h>

#define NB 2
#define NS 4096
#define ND 768
#define NH 12
#define NW 128
#define NDFF 3072
#define NHD 64
#define NCH 32   // NS/NW

typedef __attribute__((ext_vector_type(8))) short bf16x8;
typedef __attribute__((ext_vector_type(4))) short s16x4;
typedef __attribute__((ext_vector_type(4))) float f32x4;

__device__ __forceinline__ float bf2f(short u) {
    union { unsigned int i; float f; } c;
    c.i = ((unsigned int)(unsigned short)u) << 16;
    return c.f;
}
__device__ __forceinline__ short f2bf(float f) {
    union { float f; unsigned int i; } c;
    c.f = f;
    unsigned int x = c.i;
    return (short)((x + 0x7fffu + ((x >> 16) & 1u)) >> 16);
}

__device__ __forceinline__ void gl16(const void* g, const void* l) {
    __builtin_amdgcn_global_load_lds(
        (const __attribute__((address_space(1))) void*)g,
        (__attribute__((address_space(3))) void*)l, 16, 0, 0);
}

// ---------------- cast f32 -> bf16 (vectorized) ----------------
__global__ __launch_bounds__(256) void cast_bf16(const float* __restrict__ in,
                                                 short* __restrict__ out, int n4) {
    int i = blockIdx.x * 256 + threadIdx.x;
    if (i < n4) {
        f32x4 v = ((const f32x4*)in)[i];
        s16x4 o;
        o[0] = f2bf(v[0]); o[1] = f2bf(v[1]); o[2] = f2bf(v[2]); o[3] = f2bf(v[3]);
        ((s16x4*)out)[i] = o;
    }
}

// ---------------- transpose + cast: in[K][N] f32 -> out[N][K] bf16 ----------------
__global__ __launch_bounds__(256) void transpose_cast(const float* __restrict__ in,
                                                      short* __restrict__ out,
                                                      int K, int N) {
    __shared__ float tile[32][33];
    int kb = blockIdx.y * 32, nb = blockIdx.x * 32;
    int tx = threadIdx.x & 31, ty = threadIdx.x >> 5;   // ty 0..7
    #pragma unroll
    for (int r = ty; r < 32; r += 8)
        tile[r][tx] = in[(long)(kb + r) * N + nb + tx];
    __syncthreads();
    #pragma unroll
    for (int r = ty; r < 32; r += 8)
        out[(long)(nb + r) * K + kb + tx] = f2bf(tile[tx][r]);
}

// ------------- 128x128 double-buffered GEMM: C = A[M][K] @ Bt[N][K]^T -------------
// (unchanged from Round 4 — verified working)
template<int MODE>
__global__ __launch_bounds__(256, 2) void gemmdb(
    const short* __restrict__ A,
    const short* __restrict__ Bt,
    const float* __restrict__ b0,
    const float* __restrict__ b1,
    const float* __restrict__ b2,
    void* __restrict__ outp,
    const float* __restrict__ xres,
    int M, int N, int K, int gx)
{
    __shared__ short lds[2][256 * 64];   // per buf: A[128][64] | B[128][64]
    const int KT = K >> 6;

    int cpx = gridDim.x >> 3;
    int bid = blockIdx.x;
    int tile = (bid & 7) * cpx + (bid >> 3);
    int n0 = (tile % gx) * 128;
    int m0 = (tile / gx) * 128;

    int tid = threadIdx.x;
    int wid = tid >> 6, lane = tid & 63;
    int wr = wid >> 1, wc = wid & 1;          // 2x2 waves, wave tile 64x64
    int g = lane >> 4, lr = lane & 15;

    int rl = lane >> 3, sl = lane & 7;
    int soff = (sl ^ rl) << 3;                 // k-element offset (swizzled)
    const short* gA[4];
    const short* gB[4];
    #pragma unroll
    for (int c = 0; c < 4; ++c) {
        int row = c * 32 + wid * 8 + rl;
        gA[c] = A + (long)(m0 + row) * K + soff;
        gB[c] = Bt + (long)(n0 + row) * K + soff;
    }

    f32x4 acc[4][4];
    #pragma unroll
    for (int a = 0; a < 4; ++a)
        #pragma unroll
        for (int c = 0; c < 4; ++c)
            acc[a][c] = (f32x4){0.f, 0.f, 0.f, 0.f};

    auto stage = [&](int t, int buf) {
        long ko = (long)t << 6;
        #pragma unroll
        for (int c = 0; c < 4; ++c) {
            int lbase = (c * 32 + wid * 8) * 64;
            gl16(gA[c] + ko, &lds[buf][lbase]);
            gl16(gB[c] + ko, &lds[buf][128 * 64 + lbase]);
        }
    };

    stage(0, 0);
    asm volatile("s_waitcnt vmcnt(0)" ::: "memory");
    __builtin_amdgcn_s_barrier();

    int buf = 0;
    for (int t = 0; t < KT; ++t) {
        if (t + 1 < KT) stage(t + 1, buf ^ 1);
        const short* bufA = lds[buf];
        const short* bufB = lds[buf] + 128 * 64;
        bf16x8 af[2][4], bfr[2][4];
        #pragma unroll
        for (int kk = 0; kk < 2; ++kk) {
            int ph = (((kk << 2) + g) ^ (lr & 7)) << 3;   // swizzled k-slot (elems)
            #pragma unroll
            for (int mt = 0; mt < 4; ++mt)
                af[kk][mt] = *(const bf16x8*)&bufA[(wr * 64 + mt * 16 + lr) * 64 + ph];
            #pragma unroll
            for (int nt = 0; nt < 4; ++nt)
                bfr[kk][nt] = *(const bf16x8*)&bufB[(wc * 64 + nt * 16 + lr) * 64 + ph];
        }
        #pragma unroll
        for (int kk = 0; kk < 2; ++kk)
            #pragma unroll
            for (int mt = 0; mt < 4; ++mt)
                #pragma unroll
                for (int nt = 0; nt < 4; ++nt)
                    acc[mt][nt] = __builtin_amdgcn_mfma_f32_16x16x32_bf16(
                        af[kk][mt], bfr[kk][nt], acc[mt][nt], 0, 0, 0);
        asm volatile("s_waitcnt vmcnt(0)" ::: "memory");
        __builtin_amdgcn_s_barrier();
        buf ^= 1;
    }

    // ---- epilogue
    int mr0 = m0 + wr * 64;
    int nc0 = n0 + wc * 64;
    if (MODE == 4) {
        int proj = n0 / 768;   // 0=q,1=k,2=v
        const float* bp = (proj == 0) ? b0 : (proj == 1) ? b1 : b2;
        float scl = (proj == 0) ? 0.125f : 1.0f;
        short* obase = (short*)outp + (long)proj * ((long)NB * NS * ND);
        #pragma unroll
        for (int mt = 0; mt < 4; ++mt) {
            #pragma unroll
            for (int nt = 0; nt < 4; ++nt) {
                int c = nc0 + nt * 16 + lr - proj * 768;
                int hh = c >> 6, hd = c & 63;
                float bv = bp[c];
                if (proj == 2) {
                    int m = mr0 + mt * 16 + (g << 2);
                    int bbi = m >> 12, s = m & (NS - 1);
                    s16x4 ov;
                    ov[0] = f2bf(acc[mt][nt][0] + bv);
                    ov[1] = f2bf(acc[mt][nt][1] + bv);
                    ov[2] = f2bf(acc[mt][nt][2] + bv);
                    ov[3] = f2bf(acc[mt][nt][3] + bv);
                    *(s16x4*)&obase[((long)(bbi * NH + hh) * NHD + hd) * NS + s] = ov;
                } else {
                    #pragma unroll
                    for (int i = 0; i < 4; ++i) {
                        int m = mr0 + mt * 16 + (g << 2) + i;
                        int bbi = m >> 12, s = m & (NS - 1);
                        obase[((long)(bbi * NH + hh) * NS + s) * NHD + hd] =
                            f2bf((acc[mt][nt][i] + bv) * scl);
                    }
                }
            }
        }
    } else {
        #pragma unroll
        for (int mt = 0; mt < 4; ++mt) {
            #pragma unroll
            for (int nt = 0; nt < 4; ++nt) {
                int col = nc0 + nt * 16 + lr;
                float bv = b0[col];
                #pragma unroll
                for (int i = 0; i < 4; ++i) {
                    int m = mr0 + mt * 16 + (g << 2) + i;
                    float v = acc[mt][nt][i];
                    if (MODE == 2) {
                        v = fmaxf(v + bv, 0.f);
                        ((short*)outp)[(long)m * NDFF + col] = f2bf(v);
                    } else {
                        v = v + bv + xres[(long)m * ND + col];
                        ((float*)outp)[(long)m * ND + col] = v;
                    }
                }
            }
        }
    }
}

// ---------------- band attention ----------------
#define KLD 72    // 64 + 8 pad (bf16)
#define PLD 392   // 384 + 8 pad (bf16)
#define ATT_LDS (384 * KLD * 2 + 128 * PLD * 2)   // 55296 + 100352 = 155648 B

__global__ __launch_bounds__(512) void attn_kernel(
    const short* __restrict__ qg,   // (B,H,S,HD) bf16, pre-scaled
    const short* __restrict__ kg,   // (B,H,S,HD) bf16
    const short* __restrict__ vtg,  // (B,H,HD,S) bf16
    const float* __restrict__ src,  // (B,S,D) f32
    float* __restrict__ attw,       // (B,H,S,257) f32
    float* __restrict__ x,          // (B,S,D) f32
    short* __restrict__ xb)         // (B,S,D) bf16
{
    extern __shared__ char smem[];
    short* kv = (short*)smem;                     // K tile [384][KLD] then Vt [64][PLD]
    short* pl = (short*)(smem + 384 * KLD * 2);   // P [128][PLD], normalized probs

    int blk = blockIdx.x;
    int ch = blk & 31;
    int tmp = blk >> 5;
    int h = tmp % NH;
    int b = tmp / NH;
    int tid = threadIdx.x;
    int wid = tid >> 6;
    int lane = tid & 63;
    int g = lane >> 4, lr = lane & 15;
    long bh = (long)(b * NH + h);
    long kbase = bh * NS * NHD;
    int srow0 = ch * NW;

    // stage K rows j=0..383 (key pos = srow0-128+j), zero-fill OOB
    #pragma unroll
    for (int it = 0; it < 6; ++it) {
        int idx = it * 512 + tid;
        int j = idx >> 3;
        int c = (idx & 7) << 3;
        int s = srow0 - NW + j;
        bf16x8 v = {};
        if (s >= 0 && s < NS)
            v = *(const bf16x8*)&kg[kbase + (long)s * NHD + c];
        *(bf16x8*)&kv[j * KLD + c] = v;
    }

    // T14 async-STAGE: issue V loads into registers NOW; ds_write after P-barrier.
    // HBM latency hides under QK MFMA + softmax VALU.
    bf16x8 vreg[6];
    #pragma unroll
    for (int it = 0; it < 6; ++it) {
        int idx = it * 512 + tid;
        int hd = idx / 48;
        int c = (idx % 48) << 3;
        int s0 = srow0 - NW + c;
        bf16x8 v = {};
        if (s0 >= 0 && s0 < NS)
            v = *(const bf16x8*)&vtg[(bh * NHD + hd) * NS + s0];
        vreg[it] = v;
    }

    // Q fragments for this wave's 16 rows
    int t0 = wid << 4;
    bf16x8 aq[2];
    #pragma unroll
    for (int kk = 0; kk < 2; ++kk)
        aq[kk] = *(const bf16x8*)&qg[kbase + (long)(srow0 + t0 + lr) * NHD + (kk << 5) + (g << 3)];

    __syncthreads();   // sync1: K tile visible

    // scores: 24 col-tiles of 16, K=64
    f32x4 sc[24];
    #pragma unroll
    for (int jt = 0; jt < 24; ++jt) {
        f32x4 a = (f32x4){0.f, 0.f, 0.f, 0.f};
        #pragma unroll
        for (int kk = 0; kk < 2; ++kk) {
            bf16x8 bk = *(const bf16x8*)&kv[(jt * 16 + lr) * KLD + (kk << 5) + (g << 3)];
            a = __builtin_amdgcn_mfma_f32_16x16x32_bf16(aq[kk], bk, a, 0, 0, 0);
        }
        sc[jt] = a;
    }

    // mask + row max (rows of this lane: t = t0 + g*4 + i; col j = jt*16 + lr)
    float mx[4] = {-3.0e30f, -3.0e30f, -3.0e30f, -3.0e30f};
    #pragma unroll
    for (int jt = 0; jt < 24; ++jt) {
        int j = jt * 16 + lr;
        int sp = srow0 - NW + j;
        bool pok = (sp >= 0) && (sp < NS);
        #pragma unroll
        for (int i = 0; i < 4; ++i) {
            int t = t0 + (g << 2) + i;
            bool ok = pok && (j >= t) && (j <= t + 2 * NW);
            float v = ok ? sc[jt][i] : -3.0e30f;
            sc[jt][i] = v;
            mx[i] = fmaxf(mx[i], v);
        }
    }
    #pragma unroll
    for (int m = 1; m < 16; m <<= 1) {
        #pragma unroll
        for (int i = 0; i < 4; ++i)
            mx[i] = fmaxf(mx[i], __shfl_xor(mx[i], m, 64));
    }
    float sm[4] = {0.f, 0.f, 0.f, 0.f};
    #pragma unroll
    for (int jt = 0; jt < 24; ++jt) {
        #pragma unroll
        for (int i = 0; i < 4; ++i) {
            float v = sc[jt][i];
            float p = (v > -1.0e30f) ? __expf(v - mx[i]) : 0.0f;
            sc[jt][i] = p;
            sm[i] += p;
        }
    }
    #pragma unroll
    for (int m = 1; m < 16; m <<= 1) {
        #pragma unroll
        for (int i = 0; i < 4; ++i)
            sm[i] += __shfl_xor(sm[i], m, 64);
    }
    float inv[4];
    #pragma unroll
    for (int i = 0; i < 4; ++i) inv[i] = 1.0f / sm[i];

    // write normalized P (bf16) to LDS for PV, AND attn_w directly from regs
    // (f32 precision; 16-lane groups write 16 consecutive floats = coalesced).
    long aw = (bh * NS + srow0) * 257;
    #pragma unroll
    for (int jt = 0; jt < 24; ++jt) {
        int j = jt * 16 + lr;
        #pragma unroll
        for (int i = 0; i < 4; ++i) {
            int t = t0 + (g << 2) + i;
            float pv = sc[jt][i] * inv[i];
            pl[t * PLD + j] = f2bf(pv);
            int c = j - t;
            if (c >= 0 && c <= 2 * NW)
                attw[aw + (long)t * 257 + c] = pv;
        }
    }

    // sync2: order {QK ds_reads of kv, P ds_writes} before {V ds_writes, PV reads}.
    // Raw barrier + lgkm drain only — must NOT drain vmcnt (attn_w stores in flight).
    asm volatile("s_waitcnt lgkmcnt(0)" ::: "memory");
    __builtin_amdgcn_s_barrier();
    __builtin_amdgcn_sched_barrier(0);

    // V: registers -> LDS (overlays K region; zero-filled OOB already in regs)
    #pragma unroll
    for (int it = 0; it < 6; ++it) {
        int idx = it * 512 + tid;
        int hd = idx / 48;
        int c = (idx % 48) << 3;
        *(bf16x8*)&kv[hd * PLD + c] = vreg[it];
    }

    // sync3: V visible; again lgkm-only (attn_w stores still draining)
    asm volatile("s_waitcnt lgkmcnt(0)" ::: "memory");
    __builtin_amdgcn_s_barrier();
    __builtin_amdgcn_sched_barrier(0);

    // PV: 16 rows x 64 cols, K = 384
    f32x4 o[4];
    #pragma unroll
    for (int nt = 0; nt < 4; ++nt) o[nt] = (f32x4){0.f, 0.f, 0.f, 0.f};
    #pragma unroll
    for (int kt = 0; kt < 12; ++kt) {
        bf16x8 ap = *(const bf16x8*)&pl[(t0 + lr) * PLD + (kt << 5) + (g << 3)];
        #pragma unroll
        for (int nt = 0; nt < 4; ++nt) {
            bf16x8 bv = *(const bf16x8*)&kv[(nt * 16 + lr) * PLD + (kt << 5) + (g << 3)];
            o[nt] = __builtin_amdgcn_mfma_f32_16x16x32_bf16(ap, bv, o[nt], 0, 0, 0);
        }
    }

    // x = src + context
    #pragma unroll
    for (int nt = 0; nt < 4; ++nt) {
        int d = nt * 16 + lr;
        int dcol = h * NHD + d;
        #pragma unroll
        for (int i = 0; i < 4; ++i) {
            int t = t0 + (g << 2) + i;
            long row = (long)b * NS + srow0 + t;
            float v = o[nt][i] + src[row * ND + dcol];
            x[row * ND + dcol] = v;
            xb[row * ND + dcol] = f2bf(v);
        }
    }
}

// ---------------- layernorm (in-place on y) ----------------
__global__ __launch_bounds__(256) void ln_kernel(float* __restrict__ y,
                                                 const float* __restrict__ g2,
                                                 const float* __restrict__ beta2) {
    int row = blockIdx.x;
    long base = (long)row * ND;
    int tid = threadIdx.x;
    float v[3];
    float s = 0.f, ss = 0.f;
    #pragma unroll
    for (int i = 0; i < 3; ++i) {
        v[i] = y[base + i * 256 + tid];
        s += v[i];
        ss += v[i] * v[i];
    }
    #pragma unroll
    for (int m = 1; m < 64; m <<= 1) {
        s += __shfl_xor(s, m, 64);
        ss += __shfl_xor(ss, m, 64);
    }
    __shared__ float red[8];
    int wid = tid >> 6, lane = tid & 63;
    if (lane == 0) { red[wid] = s; red[wid + 4] = ss; }
    __syncthreads();
    s = red[0] + red[1] + red[2] + red[3];
    ss = red[4] + red[5] + red[6] + red[7];
    float mu = s * (1.0f / ND);
    float var = ss * (1.0f / ND) - mu * mu;
    float rstd = rsqrtf(var + 1e-6f);
    #pragma unroll
    for (int i = 0; i < 3; ++i) {
        int c = i * 256 + tid;
        y[base + c] = g2[c] * (v[i] - mu) * rstd + beta2[c];
    }
}

extern "C" void kernel_launch(void* const* d_in, const int* in_sizes, int n_in,
                              void* d_out, int out_size, void* d_ws, size_t ws_size,
                              hipStream_t stream) {
    const float* src  = (const float*)d_in[0];
    const float* Wq   = (const float*)d_in[1];
    const float* bq   = (const float*)d_in[2];
    const float* Wk   = (const float*)d_in[3];
    const float* bk   = (const float*)d_in[4];
    const float* Wv   = (const float*)d_in[5];
    const float* bv   = (const float*)d_in[6];
    const float* W1   = (const float*)d_in[7];
    const float* b1   = (const float*)d_in[8];
    const float* W2   = (const float*)d_in[9];
    const float* b2   = (const float*)d_in[10];
    const float* g2   = (const float*)d_in[11];
    const float* bt2  = (const float*)d_in[12];

    float* out  = (float*)d_out;                       // y, then LN result in-place
    float* attw = out + (long)NB * NS * ND;

    char* ws = (char*)d_ws;
    const size_t SZ_XF  = (size_t)NB * NS * ND * 4;    // 25165824
    const size_t SZ_XB  = (size_t)NB * NS * ND * 2;    // 12582912
    const size_t SZ_W1T = (size_t)ND * NDFF * 2;       // 4718592
    const size_t SZ_W2T = (size_t)NDFF * ND * 2;       // 4718592
    const size_t SZ_QKV = (size_t)NB * NS * ND * 2;    // 12582912 each
    const size_t SZ_WT  = (size_t)ND * ND * 2;         // 1179648 each

    float* x_f32 = (float*)ws;
    short* x_bf  = (short*)(ws + SZ_XF);
    short* W1T   = (short*)(ws + SZ_XF + SZ_XB);
    short* W2T   = (short*)(ws + SZ_XF + SZ_XB + SZ_W1T);
    char*  regA  = ws + SZ_XF + SZ_XB + SZ_W1T + SZ_W2T;
    short* srcb  = (short*)regA;
    short* WqT   = (short*)(regA + SZ_QKV);            // rows 0..767   }  contiguous
    short* WkT   = (short*)(regA + SZ_QKV + SZ_WT);    // rows 768..1535}  Wqkv^T
    short* WvT   = (short*)(regA + SZ_QKV + 2 * SZ_WT);// rows 1536..2303} [2304][768]
    short* qb    = (short*)(regA + SZ_QKV + 3 * SZ_WT);
    short* kb_   = (short*)(regA + 2 * SZ_QKV + 3 * SZ_WT);
    short* vb_   = (short*)(regA + 3 * SZ_QKV + 3 * SZ_WT);
    short* hbuf  = (short*)regA;   // aliases srcb..vb_ (dead after attention)

    const int M = NB * NS;   // 8192

    // casts / transposes
    cast_bf16<<<(M * ND / 4 + 255) / 256, 256, 0, stream>>>(src, srcb, M * ND / 4);
    transpose_cast<<<dim3(ND / 32, ND / 32), 256, 0, stream>>>(Wq, WqT, ND, ND);
    transpose_cast<<<dim3(ND / 32, ND / 32), 256, 0, stream>>>(Wk, WkT, ND, ND);
    transpose_cast<<<dim3(ND / 32, ND / 32), 256, 0, stream>>>(Wv, WvT, ND, ND);
    transpose_cast<<<dim3(NDFF / 32, ND / 32), 256, 0, stream>>>(W1, W1T, ND, NDFF);
    transpose_cast<<<dim3(ND / 32, NDFF / 32), 256, 0, stream>>>(W2, W2T, NDFF, ND);

    // fused QKV projection (N = 2304 = q|k|v), grid 18*64 = 1152 (div by 8)
    gemmdb<4><<<(2304 / 128) * (M / 128), 256, 0, stream>>>(
        srcb, WqT, bq, bk, bv, qb, nullptr, M, 2304, ND, 2304 / 128);

    // band attention
    (void)hipFuncSetAttribute(reinterpret_cast<const void*>(attn_kernel),
                              hipFuncAttributeMaxDynamicSharedMemorySize, ATT_LDS);
    attn_kernel<<<NB * NH * NCH, 512, ATT_LDS, stream>>>(qb, kb_, vb_, src, attw, x_f32, x_bf);

    // FFN: grids 24*64 = 1536 and 6*64 = 384 (both div by 8)
    gemmdb<2><<<(NDFF / 128) * (M / 128), 256, 0, stream>>>(
        x_bf, W1T, b1, b1, b1, hbuf, nullptr, M, NDFF, ND, NDFF / 128);
    gemmdb<3><<<(ND / 128) * (M / 128), 256, 0, stream>>>(
        hbuf, W2T, b2, b2, b2, out, x_f32, M, ND, NDFF, ND / 128);

    // LayerNorm in-place
    ln_kernel<<<M, 256, 0, stream>>>(out, g2, bt2);
}